// Round 8
// baseline (2004.493 us; speedup 1.0000x reference)
//
#include <hip/hip_runtime.h>
#include <hip/hip_fp16.h>
#include <stddef.h>

#define NPTS 16384
#define NB   16
#define NS   512
#define NK   32
#define CNTF 262144.0f

// workspace layout (bytes)
static constexpr size_t O_NXYZ = 32768;      // float[16*512*3]
static constexpr size_t O_IDX  = 131072;     // int[16*512*32]
static constexpr size_t O_SC   = 1179648;    // float[512]
static constexpr size_t O_P1   = 1181696;    // float[1024*128]
static constexpr size_t O_P2   = 1705984;    // float[2048*128]
static constexpr size_t O_P3   = 2754560;    // float[2048*256]
static constexpr size_t O_MX   = 4851712;    // __half2[16*512*128] packed (mx,mn)
static constexpr size_t O_FLG  = 9046016;    // u64 flags[511][16][4] = 261632 B (old O_MN, free)
static constexpr size_t O_Y1   = 13240320;   // float[262144*64]
static constexpr size_t O_Y2   = 80349184;   // float[262144*64]

#define DPP_ROR_FMAX(var, n) { \
    int _r = __builtin_amdgcn_update_dpp(0, __float_as_int(var), 0x120 + (n), 0xF, 0xF, false); \
    var = fmaxf(var, __int_as_float(_r)); }

#define DPP_ROR_UMIN(var, n) { \
    int _r = __builtin_amdgcn_update_dpp(0, (var), 0x120 + (n), 0xF, 0xF, false); \
    var = ((unsigned)_r < (unsigned)(var)) ? _r : (var); }

#define DPP_ROR_LEX(vv, ii, n) { \
    int _rv = __builtin_amdgcn_update_dpp(0, __float_as_int(vv), 0x120 + (n), 0xF, 0xF, false); \
    int _ri = __builtin_amdgcn_update_dpp(0, (ii), 0x120 + (n), 0xF, 0xF, false); \
    float _ov = __int_as_float(_rv); \
    bool _tk = (_ov > (vv)) || (_ov == (vv) && _ri < (ii)); \
    vv = _tk ? _ov : (vv); ii = _tk ? _ri : (ii); }

// ---- FPS: 4 blocks/batch (64 blocks), quarter-points in regs, full sxy in LDS,
//      cross-block argmax via u64-packed device-scope atomic slots per iteration ----
__global__ __launch_bounds__(1024, 4) void fps_kernel(const float* __restrict__ xyz,
    float* __restrict__ out_nx, float* __restrict__ nxyz_c,
    unsigned long long* __restrict__ flags)
{
    const int bb = blockIdx.x >> 2;   // batch
    const int g  = blockIdx.x & 3;    // quarter
    const int t  = threadIdx.x;       // 0..1023
    const int lane = t & 63;
    const int w  = t >> 6;            // 0..15
    const float* __restrict__ xb = xyz + (size_t)bb * (3 * NPTS);

    __shared__ float sxy[2 * NPTS];   // 128 KiB: full (x,y) copy for winner broadcast
    __shared__ float cand_v[2][16];
    __shared__ int   cand_i[2][16];
    __shared__ unsigned long long s_win[2];

    // full sxy copy (all 16384 points)
    for (int i = 0; i < 16; ++i) {
        int p = i * 1024 + t;
        sxy[2 * p]     = xb[p];
        sxy[2 * p + 1] = xb[NPTS + p];
    }
    // own quarter: 4 slots/thread, all state in regs
    float x0, x1, x2, x3, y0, y1, y2, y3, z0, z1, z2, z3, q0, q1, q2, q3;
#define FPS_INIT(i) { int p = (g << 12) + ((i) << 10) + t; \
    x##i = xb[p]; y##i = xb[NPTS + p]; z##i = xb[2 * NPTS + p]; q##i = 1e10f; }
    FPS_INIT(0) FPS_INIT(1) FPS_INIT(2) FPS_INIT(3)
#undef FPS_INIT
    __syncthreads();

    float cx = xb[0], cy = xb[NPTS], cz = xb[2 * NPTS];

    for (int it = 0; it < NS; ++it) {
        if (g == 0 && t == 0) {
            out_nx[(bb * 3 + 0) * NS + it] = cx;
            out_nx[(bb * 3 + 1) * NS + it] = cy;
            out_nx[(bb * 3 + 2) * NS + it] = cz;
            float* nc = nxyz_c + ((size_t)(bb * NS + it)) * 3;
            nc[0] = cx; nc[1] = cy; nc[2] = cz;
        }
        if (it == NS - 1) break;
        const int par = it & 1;
        // ---- phase A: 4 slots, pure-register (expression form identical) ----
#define FPS_SLOT(i) { \
        float ddx = x##i - cx, ddy = y##i - cy, ddz = z##i - cz; \
        float dd = ddx * ddx + ddy * ddy + ddz * ddz; \
        q##i = fminf(q##i, dd); }
        FPS_SLOT(0) FPS_SLOT(1) FPS_SLOT(2) FPS_SLOT(3)
#undef FPS_SLOT
        float m = fmaxf(fmaxf(q0, q1), fmaxf(q2, q3));
        // wave max via DPP + xor16 + xor32
        DPP_ROR_FMAX(m, 1) DPP_ROR_FMAX(m, 2) DPP_ROR_FMAX(m, 4) DPP_ROR_FMAX(m, 8)
        m = fmaxf(m, __int_as_float(__builtin_amdgcn_ds_swizzle(__float_as_int(m), 0x401F)));
        m = fmaxf(m, __shfl_xor(m, 32));
        // smallest matching slot -> global point index
        int slot = 0x7fffffff;
        slot = (q3 == m) ? 3 : slot; slot = (q2 == m) ? 2 : slot;
        slot = (q1 == m) ? 1 : slot; slot = (q0 == m) ? 0 : slot;
        int gi = (slot == 0x7fffffff) ? 0x7fffffff : ((g << 12) | (slot << 10) | t);
        DPP_ROR_UMIN(gi, 1) DPP_ROR_UMIN(gi, 2) DPP_ROR_UMIN(gi, 4) DPP_ROR_UMIN(gi, 8)
        { int r = __builtin_amdgcn_ds_swizzle(gi, 0x401F);
          gi = ((unsigned)r < (unsigned)gi) ? r : gi; }
        { int r = __shfl_xor(gi, 32);
          gi = ((unsigned)r < (unsigned)gi) ? r : gi; }
        if (lane == 0) { cand_v[par][w] = m; cand_i[par][w] = gi; }
        __syncthreads();
        // ---- block lex-reduce over 16 wave candidates (DPP, all threads) ----
        {
            const int j = lane & 15;
            float v = cand_v[par][j];
            int  i0 = cand_i[par][j];
            DPP_ROR_LEX(v, i0, 1) DPP_ROR_LEX(v, i0, 2)
            DPP_ROR_LEX(v, i0, 4) DPP_ROR_LEX(v, i0, 8)
            // ---- cross-block exchange: u64-packed (v desc, index asc) ----
            if (t == 0) {
                unsigned long long* f = flags + ((size_t)it << 6) + (bb << 2);
                unsigned long long pw =
                    ((unsigned long long)(unsigned)__float_as_int(v) << 32)
                    | (unsigned)(65535 - i0);
                __hip_atomic_store(&f[g], pw, __ATOMIC_RELEASE, __HIP_MEMORY_SCOPE_AGENT);
                unsigned long long a0 = 0, a1 = 0, a2 = 0, a3 = 0;
                for (;;) {
                    if (!a0) a0 = __hip_atomic_load(&f[0], __ATOMIC_ACQUIRE, __HIP_MEMORY_SCOPE_AGENT);
                    if (!a1) a1 = __hip_atomic_load(&f[1], __ATOMIC_ACQUIRE, __HIP_MEMORY_SCOPE_AGENT);
                    if (!a2) a2 = __hip_atomic_load(&f[2], __ATOMIC_ACQUIRE, __HIP_MEMORY_SCOPE_AGENT);
                    if (!a3) a3 = __hip_atomic_load(&f[3], __ATOMIC_ACQUIRE, __HIP_MEMORY_SCOPE_AGENT);
                    if (a0 && a1 && a2 && a3) break;
                }
                unsigned long long wn = a0 > a1 ? a0 : a1;
                unsigned long long wm = a2 > a3 ? a2 : a3;
                s_win[par] = wn > wm ? wn : wm;
            }
        }
        __syncthreads();
        {
            const unsigned long long win = s_win[par];
            const int gw = 65535 - (int)(win & 0xFFFFull);
            const float2 cxy = *(const float2*)&sxy[2 * gw];  // uniform addr: broadcast
            cx = cxy.x; cy = cxy.y;
            cz = xb[2 * NPTS + gw];                           // uniform, L1-hot
        }
    }
}

// ---------------- Ball query: one wave per (b,s), first-32-hits scan ----------------
__global__ __launch_bounds__(256) void ballq_kernel(const float* __restrict__ xyz,
    const float* __restrict__ nxyz_c, int* __restrict__ idx)
{
    const int gw = (blockIdx.x * 256 + threadIdx.x) >> 6;
    const int lane = threadIdx.x & 63;
    const int b = gw >> 9;
    const float* xb = xyz + (size_t)b * (3 * NPTS);
    const float* a = nxyz_c + (size_t)gw * 3;
    const float ax = a[0], ay = a[1], az = a[2];
    const float aa = ax * ax + ay * ay + az * az;
    const unsigned long long lmask = (lane == 63) ? 0x7fffffffffffffffull
                                                  : ((1ull << lane) - 1ull);
    int cnt = 0, first = -1;
    int* op = idx + (size_t)gw * NK;
    for (int base = 0; base < NPTS; base += 64) {
        int p = base + lane;
        float bx = xb[p], by = xb[NPTS + p], bz = xb[2 * NPTS + p];
        float bb = bx * bx + by * by + bz * bz;
        float ab = ax * bx + ay * by + az * bz;
        float sq = (aa - 2.0f * ab) + bb;
        bool hit = !(sq > 0.04f);
        unsigned long long m = __ballot(hit);
        if (m) {
            if (first < 0) first = base + (__ffsll((unsigned long long)m) - 1);
            if (hit) {
                int slot = cnt + __popcll(m & lmask);
                if (slot < NK) op[slot] = p;
            }
            cnt += __popcll(m);
            if (cnt >= NK) break;
        }
    }
    if (cnt < NK && lane >= cnt && lane < NK) op[lane] = first;
}

// ---------------- Conv1 (9->64) + stats partials ----------------
__global__ __launch_bounds__(256) void conv1_kernel(const float* __restrict__ xyz,
    const float* __restrict__ points, const float* __restrict__ nxyz_c,
    const int* __restrict__ idx, const float* __restrict__ W0, const float* __restrict__ b0,
    float* __restrict__ y1, float* __restrict__ part)
{
    const int lane = threadIdx.x & 63;
    const int w = threadIdx.x >> 6;
    const int wid = blockIdx.x * 4 + w;
    float wr[9];
#pragma unroll
    for (int c = 0; c < 9; ++c) wr[c] = W0[lane * 9 + c];
    const float bias = b0[lane];
    float sum = 0.f, sq = 0.f;
    const int r0 = wid * 64;
    for (int rr = 0; rr < 64; ++rr) {
        int r = r0 + rr;
        int b = r >> 14;
        int s = (r >> 5) & 511;
        int pidx = idx[r];
        const float* xb = xyz + (size_t)b * (3 * NPTS);
        const float* pb = points + (size_t)b * (6 * NPTS);
        const float* nc = nxyz_c + ((size_t)(b * NS + s)) * 3;
        float f0 = xb[pidx] - nc[0];
        float f1 = xb[NPTS + pidx] - nc[1];
        float f2 = xb[2 * NPTS + pidx] - nc[2];
        float f3 = pb[pidx];
        float f4 = pb[NPTS + pidx];
        float f5 = pb[2 * NPTS + pidx];
        float f6 = pb[3 * NPTS + pidx];
        float f7 = pb[4 * NPTS + pidx];
        float f8 = pb[5 * NPTS + pidx];
        float acc = bias;
        acc = fmaf(wr[0], f0, acc); acc = fmaf(wr[1], f1, acc); acc = fmaf(wr[2], f2, acc);
        acc = fmaf(wr[3], f3, acc); acc = fmaf(wr[4], f4, acc); acc = fmaf(wr[5], f5, acc);
        acc = fmaf(wr[6], f6, acc); acc = fmaf(wr[7], f7, acc); acc = fmaf(wr[8], f8, acc);
        y1[(size_t)r * 64 + lane] = acc;
        sum += acc; sq = fmaf(acc, acc, sq);
    }
    __shared__ float sred[4 * 128];
    sred[w * 128 + lane] = sum;
    sred[w * 128 + 64 + lane] = sq;
    __syncthreads();
    if (threadIdx.x < 128) {
        float tot = sred[threadIdx.x] + sred[128 + threadIdx.x]
                  + sred[256 + threadIdx.x] + sred[384 + threadIdx.x];
        part[(size_t)blockIdx.x * 128 + threadIdx.x] = tot;
    }
}

// ---------------- Conv2 (64->64) as LDS-tiled register-blocked GEMM ----------------
__global__ __launch_bounds__(256) void conv2_kernel(const float* __restrict__ y1,
    const float* __restrict__ W1, const float* __restrict__ b1,
    const float* __restrict__ scales, float* __restrict__ y2, float* __restrict__ part)
{
    __shared__ float aT[64 * 128];    // [c][r]
    __shared__ float wT[64 * 64];     // [c][o]
    __shared__ float sred[4 * 128];
    __shared__ float ssc[128];
    const int tid = threadIdx.x;
    const int r0 = blockIdx.x * 128;

    if (tid < 128) ssc[tid] = scales[tid];
    {
        const int o = tid & 63;
        const int cseg = (tid >> 6) * 16;
#pragma unroll
        for (int j = 0; j < 4; ++j) {
            const float4 v = *(const float4*)&W1[o * 64 + cseg + j * 4];
            wT[(cseg + j * 4 + 0) * 64 + o] = v.x;
            wT[(cseg + j * 4 + 1) * 64 + o] = v.y;
            wT[(cseg + j * 4 + 2) * 64 + o] = v.z;
            wT[(cseg + j * 4 + 3) * 64 + o] = v.w;
        }
    }
    __syncthreads();
    {
        const int r = tid & 127;
        const int cs = (tid >> 7) * 32;
#pragma unroll
        for (int j = 0; j < 8; ++j) {
            const int c = cs + j * 4;
            const float4 v = *(const float4*)&y1[(size_t)(r0 + r) * 64 + c];
            aT[(c + 0) * 128 + r] = fmaxf(fmaf(ssc[c + 0], v.x, ssc[64 + c + 0]), 0.f);
            aT[(c + 1) * 128 + r] = fmaxf(fmaf(ssc[c + 1], v.y, ssc[64 + c + 1]), 0.f);
            aT[(c + 2) * 128 + r] = fmaxf(fmaf(ssc[c + 2], v.z, ssc[64 + c + 2]), 0.f);
            aT[(c + 3) * 128 + r] = fmaxf(fmaf(ssc[c + 3], v.w, ssc[64 + c + 3]), 0.f);
        }
    }
    __syncthreads();

    const int wv = tid >> 6;
    const int lane = tid & 63;
    const int tr = lane >> 4;
    const int to = lane & 15;
    const int rbase = wv * 32 + tr * 8;
    const int obase = to * 4;

    const float4 bv = *(const float4*)&b1[obase];
    float4 acc[8];
#pragma unroll
    for (int rr = 0; rr < 8; ++rr) acc[rr] = bv;

#pragma unroll 4
    for (int c = 0; c < 64; ++c) {
        const float4 a0 = *(const float4*)&aT[c * 128 + rbase];
        const float4 a1 = *(const float4*)&aT[c * 128 + rbase + 4];
        const float4 wf = *(const float4*)&wT[c * 64 + obase];
        const float ar[8] = {a0.x, a0.y, a0.z, a0.w, a1.x, a1.y, a1.z, a1.w};
#pragma unroll
        for (int rr = 0; rr < 8; ++rr) {
            acc[rr].x = fmaf(ar[rr], wf.x, acc[rr].x);
            acc[rr].y = fmaf(ar[rr], wf.y, acc[rr].y);
            acc[rr].z = fmaf(ar[rr], wf.z, acc[rr].z);
            acc[rr].w = fmaf(ar[rr], wf.w, acc[rr].w);
        }
    }
    float4 s = {0.f, 0.f, 0.f, 0.f}, q = {0.f, 0.f, 0.f, 0.f};
#pragma unroll
    for (int rr = 0; rr < 8; ++rr) {
        *(float4*)&y2[(size_t)(r0 + rbase + rr) * 64 + obase] = acc[rr];
        s.x += acc[rr].x; s.y += acc[rr].y; s.z += acc[rr].z; s.w += acc[rr].w;
        q.x = fmaf(acc[rr].x, acc[rr].x, q.x);
        q.y = fmaf(acc[rr].y, acc[rr].y, q.y);
        q.z = fmaf(acc[rr].z, acc[rr].z, q.z);
        q.w = fmaf(acc[rr].w, acc[rr].w, q.w);
    }
#pragma unroll
    for (int off = 16; off <= 32; off <<= 1) {
        s.x += __shfl_xor(s.x, off); s.y += __shfl_xor(s.y, off);
        s.z += __shfl_xor(s.z, off); s.w += __shfl_xor(s.w, off);
        q.x += __shfl_xor(q.x, off); q.y += __shfl_xor(q.y, off);
        q.z += __shfl_xor(q.z, off); q.w += __shfl_xor(q.w, off);
    }
    if (tr == 0) {
        sred[wv * 128 + obase + 0] = s.x; sred[wv * 128 + obase + 1] = s.y;
        sred[wv * 128 + obase + 2] = s.z; sred[wv * 128 + obase + 3] = s.w;
        sred[wv * 128 + 64 + obase + 0] = q.x; sred[wv * 128 + 64 + obase + 1] = q.y;
        sred[wv * 128 + 64 + obase + 2] = q.z; sred[wv * 128 + 64 + obase + 3] = q.w;
    }
    __syncthreads();
    if (tid < 128) {
        float tot = sred[tid] + sred[128 + tid] + sred[256 + tid] + sred[384 + tid];
        part[(size_t)blockIdx.x * 128 + tid] = tot;
    }
}

// ---------------- Conv3 (64->128) GEMM + stats + packed f16 max/min over K ----------------
__global__ __launch_bounds__(256) void conv3_kernel(const float* __restrict__ y2,
    const float* __restrict__ W2, const float* __restrict__ b2,
    const float* __restrict__ scales, __half2* __restrict__ mxmn, float* __restrict__ part)
{
    __shared__ float aT[64 * 128];    // [c][r]
    __shared__ float wT[64 * 128];    // [c][o]
    __shared__ float sred[4 * 256];
    __shared__ float ssc[128];
    const int tid = threadIdx.x;
    const int r0 = blockIdx.x * 128;

    if (tid < 128) ssc[tid] = scales[128 + tid];
    {
        const int o = tid & 127;
        const int cs = (tid >> 7) * 32;
#pragma unroll
        for (int j = 0; j < 8; ++j) {
            const float4 v = *(const float4*)&W2[(size_t)o * 64 + cs + j * 4];
            wT[(cs + j * 4 + 0) * 128 + o] = v.x;
            wT[(cs + j * 4 + 1) * 128 + o] = v.y;
            wT[(cs + j * 4 + 2) * 128 + o] = v.z;
            wT[(cs + j * 4 + 3) * 128 + o] = v.w;
        }
    }
    __syncthreads();
    {
        const int r = tid & 127;
        const int cs = (tid >> 7) * 32;
#pragma unroll
        for (int j = 0; j < 8; ++j) {
            const int c = cs + j * 4;
            const float4 v = *(const float4*)&y2[(size_t)(r0 + r) * 64 + c];
            aT[(c + 0) * 128 + r] = fmaxf(fmaf(ssc[c + 0], v.x, ssc[64 + c + 0]), 0.f);
            aT[(c + 1) * 128 + r] = fmaxf(fmaf(ssc[c + 1], v.y, ssc[64 + c + 1]), 0.f);
            aT[(c + 2) * 128 + r] = fmaxf(fmaf(ssc[c + 2], v.z, ssc[64 + c + 2]), 0.f);
            aT[(c + 3) * 128 + r] = fmaxf(fmaf(ssc[c + 3], v.w, ssc[64 + c + 3]), 0.f);
        }
    }
    __syncthreads();

    const int wv = tid >> 6;
    const int lane = tid & 63;
    const int tr = lane >> 4;
    const int to = lane & 15;
    const int rbase = wv * 32 + tr * 8;
    const int ol = to * 4;
    const int oh = 64 + to * 4;

    const float4 bl = *(const float4*)&b2[ol];
    const float4 bh = *(const float4*)&b2[oh];
    float4 accl[8], acch[8];
#pragma unroll
    for (int rr = 0; rr < 8; ++rr) { accl[rr] = bl; acch[rr] = bh; }

#pragma unroll 2
    for (int c = 0; c < 64; ++c) {
        const float4 a0 = *(const float4*)&aT[c * 128 + rbase];
        const float4 a1 = *(const float4*)&aT[c * 128 + rbase + 4];
        const float4 w0 = *(const float4*)&wT[c * 128 + ol];
        const float4 w1 = *(const float4*)&wT[c * 128 + oh];
        const float ar[8] = {a0.x, a0.y, a0.z, a0.w, a1.x, a1.y, a1.z, a1.w};
#pragma unroll
        for (int rr = 0; rr < 8; ++rr) {
            accl[rr].x = fmaf(ar[rr], w0.x, accl[rr].x);
            accl[rr].y = fmaf(ar[rr], w0.y, accl[rr].y);
            accl[rr].z = fmaf(ar[rr], w0.z, accl[rr].z);
            accl[rr].w = fmaf(ar[rr], w0.w, accl[rr].w);
            acch[rr].x = fmaf(ar[rr], w1.x, acch[rr].x);
            acch[rr].y = fmaf(ar[rr], w1.y, acch[rr].y);
            acch[rr].z = fmaf(ar[rr], w1.z, acch[rr].z);
            acch[rr].w = fmaf(ar[rr], w1.w, acch[rr].w);
        }
    }
    float4 sl = {0,0,0,0}, ql = {0,0,0,0}, sh4 = {0,0,0,0}, qh = {0,0,0,0};
    float4 mxl = accl[0], mnl = accl[0], mxh = acch[0], mnh = acch[0];
#pragma unroll
    for (int rr = 0; rr < 8; ++rr) {
        sl.x += accl[rr].x; sl.y += accl[rr].y; sl.z += accl[rr].z; sl.w += accl[rr].w;
        sh4.x += acch[rr].x; sh4.y += acch[rr].y; sh4.z += acch[rr].z; sh4.w += acch[rr].w;
        ql.x = fmaf(accl[rr].x, accl[rr].x, ql.x); ql.y = fmaf(accl[rr].y, accl[rr].y, ql.y);
        ql.z = fmaf(accl[rr].z, accl[rr].z, ql.z); ql.w = fmaf(accl[rr].w, accl[rr].w, ql.w);
        qh.x = fmaf(acch[rr].x, acch[rr].x, qh.x); qh.y = fmaf(acch[rr].y, acch[rr].y, qh.y);
        qh.z = fmaf(acch[rr].z, acch[rr].z, qh.z); qh.w = fmaf(acch[rr].w, acch[rr].w, qh.w);
        mxl.x = fmaxf(mxl.x, accl[rr].x); mnl.x = fminf(mnl.x, accl[rr].x);
        mxl.y = fmaxf(mxl.y, accl[rr].y); mnl.y = fminf(mnl.y, accl[rr].y);
        mxl.z = fmaxf(mxl.z, accl[rr].z); mnl.z = fminf(mnl.z, accl[rr].z);
        mxl.w = fmaxf(mxl.w, accl[rr].w); mnl.w = fminf(mnl.w, accl[rr].w);
        mxh.x = fmaxf(mxh.x, acch[rr].x); mnh.x = fminf(mnh.x, acch[rr].x);
        mxh.y = fmaxf(mxh.y, acch[rr].y); mnh.y = fminf(mnh.y, acch[rr].y);
        mxh.z = fmaxf(mxh.z, acch[rr].z); mnh.z = fminf(mnh.z, acch[rr].z);
        mxh.w = fmaxf(mxh.w, acch[rr].w); mnh.w = fminf(mnh.w, acch[rr].w);
    }
#pragma unroll
    for (int off = 16; off <= 32; off <<= 1) {
        sl.x += __shfl_xor(sl.x, off); sl.y += __shfl_xor(sl.y, off);
        sl.z += __shfl_xor(sl.z, off); sl.w += __shfl_xor(sl.w, off);
        sh4.x += __shfl_xor(sh4.x, off); sh4.y += __shfl_xor(sh4.y, off);
        sh4.z += __shfl_xor(sh4.z, off); sh4.w += __shfl_xor(sh4.w, off);
        ql.x += __shfl_xor(ql.x, off); ql.y += __shfl_xor(ql.y, off);
        ql.z += __shfl_xor(ql.z, off); ql.w += __shfl_xor(ql.w, off);
        qh.x += __shfl_xor(qh.x, off); qh.y += __shfl_xor(qh.y, off);
        qh.z += __shfl_xor(qh.z, off); qh.w += __shfl_xor(qh.w, off);
        mxl.x = fmaxf(mxl.x, __shfl_xor(mxl.x, off)); mnl.x = fminf(mnl.x, __shfl_xor(mnl.x, off));
        mxl.y = fmaxf(mxl.y, __shfl_xor(mxl.y, off)); mnl.y = fminf(mnl.y, __shfl_xor(mnl.y, off));
        mxl.z = fmaxf(mxl.z, __shfl_xor(mxl.z, off)); mnl.z = fminf(mnl.z, __shfl_xor(mnl.z, off));
        mxl.w = fmaxf(mxl.w, __shfl_xor(mxl.w, off)); mnl.w = fminf(mnl.w, __shfl_xor(mnl.w, off));
        mxh.x = fmaxf(mxh.x, __shfl_xor(mxh.x, off)); mnh.x = fminf(mnh.x, __shfl_xor(mnh.x, off));
        mxh.y = fmaxf(mxh.y, __shfl_xor(mxh.y, off)); mnh.y = fminf(mnh.y, __shfl_xor(mnh.y, off));
        mxh.z = fmaxf(mxh.z, __shfl_xor(mxh.z, off)); mnh.z = fminf(mnh.z, __shfl_xor(mnh.z, off));
        mxh.w = fmaxf(mxh.w, __shfl_xor(mxh.w, off)); mnh.w = fminf(mnh.w, __shfl_xor(mnh.w, off));
    }
    if (tr == 0) {
        const int wid = blockIdx.x * 4 + wv;
        __half2* mp = mxmn + (size_t)wid * 128;
        mp[ol + 0] = __floats2half2_rn(mxl.x, mnl.x);
        mp[ol + 1] = __floats2half2_rn(mxl.y, mnl.y);
        mp[ol + 2] = __floats2half2_rn(mxl.z, mnl.z);
        mp[ol + 3] = __floats2half2_rn(mxl.w, mnl.w);
        mp[oh + 0] = __floats2half2_rn(mxh.x, mnh.x);
        mp[oh + 1] = __floats2half2_rn(mxh.y, mnh.y);
        mp[oh + 2] = __floats2half2_rn(mxh.z, mnh.z);
        mp[oh + 3] = __floats2half2_rn(mxh.w, mnh.w);
        sred[wv * 256 + ol + 0] = sl.x; sred[wv * 256 + ol + 1] = sl.y;
        sred[wv * 256 + ol + 2] = sl.z; sred[wv * 256 + ol + 3] = sl.w;
        sred[wv * 256 + oh + 0] = sh4.x; sred[wv * 256 + oh + 1] = sh4.y;
        sred[wv * 256 + oh + 2] = sh4.z; sred[wv * 256 + oh + 3] = sh4.w;
        sred[wv * 256 + 128 + ol + 0] = ql.x; sred[wv * 256 + 128 + ol + 1] = ql.y;
        sred[wv * 256 + 128 + ol + 2] = ql.z; sred[wv * 256 + 128 + ol + 3] = ql.w;
        sred[wv * 256 + 128 + oh + 0] = qh.x; sred[wv * 256 + 128 + oh + 1] = qh.y;
        sred[wv * 256 + 128 + oh + 2] = qh.z; sred[wv * 256 + 128 + oh + 3] = qh.w;
    }
    __syncthreads();
    {
        float tot = sred[tid] + sred[256 + tid] + sred[512 + tid] + sred[768 + tid];
        part[(size_t)blockIdx.x * 256 + tid] = tot;
    }
}

// ---------------- BN stats -> per-channel scale/shift ----------------
__global__ __launch_bounds__(1024) void stats_kernel(const float* __restrict__ part,
    int nparts, int nch, const float* __restrict__ g, const float* __restrict__ be,
    float* __restrict__ scale, float* __restrict__ shift)
{
    __shared__ float s_s[1024], s_q[1024];
    const int t = threadIdx.x;
    const int groups = 1024 / nch;
    const int gid = t / nch;
    const int o = t % nch;
    const int chunk = nparts / groups;
    float sum = 0.f, sq = 0.f;
    for (int p = gid * chunk; p < (gid + 1) * chunk; ++p) {
        sum += part[(size_t)p * 2 * nch + o];
        sq  += part[(size_t)p * 2 * nch + nch + o];
    }
    s_s[t] = sum; s_q[t] = sq;
    __syncthreads();
    if (t < nch) {
        float S = 0.f, Q = 0.f;
        for (int gi = 0; gi < groups; ++gi) { S += s_s[gi * nch + o]; Q += s_q[gi * nch + o]; }
        float m = S / CNTF;
        float v = Q / CNTF - m * m;
        v = v < 0.f ? 0.f : v;
        float scv = g[o] / sqrtf(v + 1e-5f);
        scale[o] = scv;
        shift[o] = be[o] - m * scv;
    }
}

// ---------------- Final: BN3+ReLU+max via packed (mx,mn) ----------------
__global__ __launch_bounds__(256) void final_kernel(const __half2* __restrict__ mxmn,
    const float* __restrict__ scales, float* __restrict__ out)
{
    int tid = blockIdx.x * 256 + threadIdx.x;   // b*65536 + o*512 + s
    int b = tid >> 16;
    int o = (tid >> 9) & 127;
    int s = tid & 511;
    int row = (b * NS + s) * 128 + o;
    float sc = scales[256 + o], sh = scales[384 + o];
    const __half2 h = mxmn[row];
    float vmx = __low2float(h), vmn = __high2float(h);
    float y = fmaxf(fmaf(sc, vmx, sh), fmaf(sc, vmn, sh));
    out[tid] = fmaxf(y, 0.f);
}

extern "C" void kernel_launch(void* const* d_in, const int* in_sizes, int n_in,
                              void* d_out, int out_size, void* d_ws, size_t ws_size,
                              hipStream_t stream)
{
    (void)in_sizes; (void)n_in; (void)out_size; (void)ws_size;
    const float* xyz    = (const float*)d_in[0];
    const float* points = (const float*)d_in[1];
    const float* W0  = (const float*)d_in[2];
    const float* b0  = (const float*)d_in[3];
    const float* g0  = (const float*)d_in[4];
    const float* be0 = (const float*)d_in[5];
    const float* W1  = (const float*)d_in[6];
    const float* b1  = (const float*)d_in[7];
    const float* g1  = (const float*)d_in[8];
    const float* be1 = (const float*)d_in[9];
    const float* W2  = (const float*)d_in[10];
    const float* b2  = (const float*)d_in[11];
    const float* g2  = (const float*)d_in[12];
    const float* be2 = (const float*)d_in[13];

    char* ws = (char*)d_ws;
    float*   nxyz = (float*)(ws + O_NXYZ);
    int*     idx  = (int*)(ws + O_IDX);
    float*   scl  = (float*)(ws + O_SC);
    float*   p1   = (float*)(ws + O_P1);
    float*   p2   = (float*)(ws + O_P2);
    float*   p3   = (float*)(ws + O_P3);
    __half2* mxmn = (__half2*)(ws + O_MX);
    unsigned long long* flags = (unsigned long long*)(ws + O_FLG);
    float*   y1   = (float*)(ws + O_Y1);
    float*   y2   = (float*)(ws + O_Y2);
    float*   out  = (float*)d_out;

    hipMemsetAsync(flags, 0, 511 * 16 * 4 * sizeof(unsigned long long), stream);
    fps_kernel<<<64, 1024, 0, stream>>>(xyz, out, nxyz, flags);
    ballq_kernel<<<2048, 256, 0, stream>>>(xyz, nxyz, idx);
    conv1_kernel<<<1024, 256, 0, stream>>>(xyz, points, nxyz, idx, W0, b0, y1, p1);
    stats_kernel<<<1, 1024, 0, stream>>>(p1, 1024, 64, g0, be0, scl + 0, scl + 64);
    conv2_kernel<<<2048, 256, 0, stream>>>(y1, W1, b1, scl, y2, p2);
    stats_kernel<<<1, 1024, 0, stream>>>(p2, 2048, 64, g1, be1, scl + 128, scl + 192);
    conv3_kernel<<<2048, 256, 0, stream>>>(y2, W2, b2, scl, mxmn, p3);
    stats_kernel<<<1, 1024, 0, stream>>>(p3, 2048, 128, g2, be2, scl + 256, scl + 384);
    final_kernel<<<4096, 256, 0, stream>>>(mxmn, scl, out + 24576);
}

// Round 9
// 1255.010 us; speedup vs baseline: 1.5972x; 1.5972x over previous
//
#include <hip/hip_runtime.h>
#include <hip/hip_fp16.h>
#include <stddef.h>

#define NPTS 16384
#define NB   16
#define NS   512
#define NK   32
#define CNTF 262144.0f

// workspace layout (bytes)
static constexpr size_t O_NXYZ = 32768;      // float[16*512*3]
static constexpr size_t O_IDX  = 131072;     // int[16*512*32]
static constexpr size_t O_SC   = 1179648;    // float[512]
static constexpr size_t O_P1   = 1181696;    // float[1024*128]
static constexpr size_t O_P2   = 1705984;    // float[2048*128]
static constexpr size_t O_P3   = 2754560;    // float[2048*256]
static constexpr size_t O_MX   = 4851712;    // __half2[16*512*128] packed (mx,mn)
static constexpr size_t O_Y1   = 13240320;   // float[262144*64]
static constexpr size_t O_Y2   = 80349184;   // float[262144*64]

// DPP helpers. ROW_ROR:n = 0x120+n (within 16-lane rows).
// ROW_BCAST15 = 0x142 (lane15->lanes16..31, lane47->lanes48..63),
// ROW_BCAST31 = 0x143 (lane31->lanes32..63). Unselected lanes receive `old`,
// chosen as the reduction identity (0 for fmax of squared distances >= 0,
// INT_MAX for unsigned min). Result lands in lane 63 -> readlane broadcast.
#define DPP_ROR_FMAX(var, n) { \
    int _r = __builtin_amdgcn_update_dpp(0, __float_as_int(var), 0x120 + (n), 0xF, 0xF, false); \
    var = fmaxf(var, __int_as_float(_r)); }

#define DPP_ROR_UMIN(var, n) { \
    int _r = __builtin_amdgcn_update_dpp(0, (var), 0x120 + (n), 0xF, 0xF, false); \
    var = ((unsigned)_r < (unsigned)(var)) ? _r : (var); }

#define DPP_ROR_LEX(vv, ii, n) { \
    int _rv = __builtin_amdgcn_update_dpp(0, __float_as_int(vv), 0x120 + (n), 0xF, 0xF, false); \
    int _ri = __builtin_amdgcn_update_dpp(0, (ii), 0x120 + (n), 0xF, 0xF, false); \
    float _ov = __int_as_float(_rv); \
    bool _tk = (_ov > (vv)) || (_ov == (vv) && _ri < (ii)); \
    vv = _tk ? _ov : (vv); ii = _tk ? _ri : (ii); }

// ---- FPS: 1 block/batch, 1024 thr x 16 pts; DPP-only wave reduces ----
__global__ __launch_bounds__(1024, 4) void fps_kernel(const float* __restrict__ xyz,
    float* __restrict__ out_nx, float* __restrict__ nxyz_c)
{
    const int b = blockIdx.x;
    const int t = threadIdx.x;
    const int lane = t & 63;
    const int w = t >> 6;
    const float* __restrict__ xb = xyz + (size_t)b * (3 * NPTS);

    __shared__ float sxy[2 * NPTS];
    __shared__ float cand_v[2][16];
    __shared__ int   cand_i[2][16];

    float cx = xb[0], cy = xb[NPTS], cz = xb[2 * NPTS];

#define FPS_DECL(i) float z##i, q##i;
    FPS_DECL(0)  FPS_DECL(1)  FPS_DECL(2)  FPS_DECL(3)
    FPS_DECL(4)  FPS_DECL(5)  FPS_DECL(6)  FPS_DECL(7)
    FPS_DECL(8)  FPS_DECL(9)  FPS_DECL(10) FPS_DECL(11)
    FPS_DECL(12) FPS_DECL(13) FPS_DECL(14) FPS_DECL(15)

#define FPS_INIT(i) { int p = (i) * 1024 + t; \
    float xx = xb[p]; float yy = xb[NPTS + p]; \
    sxy[2 * p] = xx; sxy[2 * p + 1] = yy; \
    z##i = xb[2 * NPTS + p]; q##i = 1e10f; }
    FPS_INIT(0)  FPS_INIT(1)  FPS_INIT(2)  FPS_INIT(3)
    FPS_INIT(4)  FPS_INIT(5)  FPS_INIT(6)  FPS_INIT(7)
    FPS_INIT(8)  FPS_INIT(9)  FPS_INIT(10) FPS_INIT(11)
    FPS_INIT(12) FPS_INIT(13) FPS_INIT(14) FPS_INIT(15)
    __syncthreads();

    for (int it = 0; it < NS; ++it) {
        if (t == 0) {
            out_nx[(b * 3 + 0) * NS + it] = cx;
            out_nx[(b * 3 + 1) * NS + it] = cy;
            out_nx[(b * 3 + 2) * NS + it] = cz;
            float* nc = nxyz_c + ((size_t)(b * NS + it)) * 3;
            nc[0] = cx; nc[1] = cy; nc[2] = cz;
        }
        if (it == NS - 1) break;
        const int par = it & 1;
        // ---- phase A: dist update (expression form identical to passing rounds) ----
#define FPS_SLOT(i) { \
        float2 xy = *(const float2*)&sxy[2 * ((i) * 1024 + t)]; \
        float ddx = xy.x - cx, ddy = xy.y - cy, ddz = z##i - cz; \
        float dd = ddx * ddx + ddy * ddy + ddz * ddz; \
        q##i = fminf(q##i, dd); }
        FPS_SLOT(0)  FPS_SLOT(1)  FPS_SLOT(2)  FPS_SLOT(3)
        FPS_SLOT(4)  FPS_SLOT(5)  FPS_SLOT(6)  FPS_SLOT(7)
        FPS_SLOT(8)  FPS_SLOT(9)  FPS_SLOT(10) FPS_SLOT(11)
        FPS_SLOT(12) FPS_SLOT(13) FPS_SLOT(14) FPS_SLOT(15)
        // ---- per-thread max tree ----
        float m = fmaxf(fmaxf(fmaxf(q0,  q1),  fmaxf(q2,  q3)),
                        fmaxf(fmaxf(q4,  q5),  fmaxf(q6,  q7)));
        m = fmaxf(m, fmaxf(fmaxf(fmaxf(q8,  q9),  fmaxf(q10, q11)),
                           fmaxf(fmaxf(q12, q13), fmaxf(q14, q15))));
        // ---- wave max: DPP row-reduce + bcast15/31 (VALU-only) + readlane ----
        DPP_ROR_FMAX(m, 1) DPP_ROR_FMAX(m, 2) DPP_ROR_FMAX(m, 4) DPP_ROR_FMAX(m, 8)
        { int _r = __builtin_amdgcn_update_dpp(0, __float_as_int(m), 0x142, 0xF, 0xF, false);
          m = fmaxf(m, __int_as_float(_r)); }
        { int _r = __builtin_amdgcn_update_dpp(0, __float_as_int(m), 0x143, 0xF, 0xF, false);
          m = fmaxf(m, __int_as_float(_r)); }
        m = __int_as_float(__builtin_amdgcn_readlane(__float_as_int(m), 63));
        // ---- match pass: smallest slot with q == wave max (exact bits) ----
        int slot = 0x7fffffff;
#define FPS_MATCH(i) slot = (q##i == m) ? (i) : slot;
        FPS_MATCH(15) FPS_MATCH(14) FPS_MATCH(13) FPS_MATCH(12)
        FPS_MATCH(11) FPS_MATCH(10) FPS_MATCH(9)  FPS_MATCH(8)
        FPS_MATCH(7)  FPS_MATCH(6)  FPS_MATCH(5)  FPS_MATCH(4)
        FPS_MATCH(3)  FPS_MATCH(2)  FPS_MATCH(1)  FPS_MATCH(0)
        int gi = (slot == 0x7fffffff) ? 0x7fffffff : ((slot << 10) | t);
        // ---- wave min-index: DPP row-reduce + bcast15/31 + readlane ----
        DPP_ROR_UMIN(gi, 1) DPP_ROR_UMIN(gi, 2) DPP_ROR_UMIN(gi, 4) DPP_ROR_UMIN(gi, 8)
        { int _r = __builtin_amdgcn_update_dpp(0x7fffffff, gi, 0x142, 0xF, 0xF, false);
          gi = ((unsigned)_r < (unsigned)gi) ? _r : gi; }
        { int _r = __builtin_amdgcn_update_dpp(0x7fffffff, gi, 0x143, 0xF, 0xF, false);
          gi = ((unsigned)_r < (unsigned)gi) ? _r : gi; }
        gi = __builtin_amdgcn_readlane(gi, 63);
        if (lane == 0) { cand_v[par][w] = m; cand_i[par][w] = gi; }
        __syncthreads();   // the only barrier per iteration
        // ---- phase B: 16 candidates on lane&15, DPP lex rotate-reduce ----
        {
            const int j = lane & 15;
            float v = cand_v[par][j];
            int  i0 = cand_i[par][j];
            DPP_ROR_LEX(v, i0, 1) DPP_ROR_LEX(v, i0, 2)
            DPP_ROR_LEX(v, i0, 4) DPP_ROR_LEX(v, i0, 8)
            const float2 cxy = *(const float2*)&sxy[2 * i0];  // uniform addr: broadcast
            cx = cxy.x; cy = cxy.y;
            cz = xb[2 * NPTS + i0];                            // uniform, L1/L2-hot
        }
    }
#undef FPS_DECL
#undef FPS_INIT
#undef FPS_SLOT
#undef FPS_MATCH
}

// ---------------- Ball query: one wave per (b,s), first-32-hits scan ----------------
__global__ __launch_bounds__(256) void ballq_kernel(const float* __restrict__ xyz,
    const float* __restrict__ nxyz_c, int* __restrict__ idx)
{
    const int gw = (blockIdx.x * 256 + threadIdx.x) >> 6;
    const int lane = threadIdx.x & 63;
    const int b = gw >> 9;
    const float* xb = xyz + (size_t)b * (3 * NPTS);
    const float* a = nxyz_c + (size_t)gw * 3;
    const float ax = a[0], ay = a[1], az = a[2];
    const float aa = ax * ax + ay * ay + az * az;
    const unsigned long long lmask = (lane == 63) ? 0x7fffffffffffffffull
                                                  : ((1ull << lane) - 1ull);
    int cnt = 0, first = -1;
    int* op = idx + (size_t)gw * NK;
    for (int base = 0; base < NPTS; base += 64) {
        int p = base + lane;
        float bx = xb[p], by = xb[NPTS + p], bz = xb[2 * NPTS + p];
        float bb = bx * bx + by * by + bz * bz;
        float ab = ax * bx + ay * by + az * bz;
        float sq = (aa - 2.0f * ab) + bb;
        bool hit = !(sq > 0.04f);
        unsigned long long m = __ballot(hit);
        if (m) {
            if (first < 0) first = base + (__ffsll((unsigned long long)m) - 1);
            if (hit) {
                int slot = cnt + __popcll(m & lmask);
                if (slot < NK) op[slot] = p;
            }
            cnt += __popcll(m);
            if (cnt >= NK) break;
        }
    }
    if (cnt < NK && lane >= cnt && lane < NK) op[lane] = first;
}

// ---------------- Conv1 (9->64) + stats partials ----------------
__global__ __launch_bounds__(256) void conv1_kernel(const float* __restrict__ xyz,
    const float* __restrict__ points, const float* __restrict__ nxyz_c,
    const int* __restrict__ idx, const float* __restrict__ W0, const float* __restrict__ b0,
    float* __restrict__ y1, float* __restrict__ part)
{
    const int lane = threadIdx.x & 63;
    const int w = threadIdx.x >> 6;
    const int wid = blockIdx.x * 4 + w;
    float wr[9];
#pragma unroll
    for (int c = 0; c < 9; ++c) wr[c] = W0[lane * 9 + c];
    const float bias = b0[lane];
    float sum = 0.f, sq = 0.f;
    const int r0 = wid * 64;
    for (int rr = 0; rr < 64; ++rr) {
        int r = r0 + rr;
        int b = r >> 14;
        int s = (r >> 5) & 511;
        int pidx = idx[r];
        const float* xb = xyz + (size_t)b * (3 * NPTS);
        const float* pb = points + (size_t)b * (6 * NPTS);
        const float* nc = nxyz_c + ((size_t)(b * NS + s)) * 3;
        float f0 = xb[pidx] - nc[0];
        float f1 = xb[NPTS + pidx] - nc[1];
        float f2 = xb[2 * NPTS + pidx] - nc[2];
        float f3 = pb[pidx];
        float f4 = pb[NPTS + pidx];
        float f5 = pb[2 * NPTS + pidx];
        float f6 = pb[3 * NPTS + pidx];
        float f7 = pb[4 * NPTS + pidx];
        float f8 = pb[5 * NPTS + pidx];
        float acc = bias;
        acc = fmaf(wr[0], f0, acc); acc = fmaf(wr[1], f1, acc); acc = fmaf(wr[2], f2, acc);
        acc = fmaf(wr[3], f3, acc); acc = fmaf(wr[4], f4, acc); acc = fmaf(wr[5], f5, acc);
        acc = fmaf(wr[6], f6, acc); acc = fmaf(wr[7], f7, acc); acc = fmaf(wr[8], f8, acc);
        y1[(size_t)r * 64 + lane] = acc;
        sum += acc; sq = fmaf(acc, acc, sq);
    }
    __shared__ float sred[4 * 128];
    sred[w * 128 + lane] = sum;
    sred[w * 128 + 64 + lane] = sq;
    __syncthreads();
    if (threadIdx.x < 128) {
        float tot = sred[threadIdx.x] + sred[128 + threadIdx.x]
                  + sred[256 + threadIdx.x] + sred[384 + threadIdx.x];
        part[(size_t)blockIdx.x * 128 + threadIdx.x] = tot;
    }
}

// ---------------- Conv2 (64->64) as LDS-tiled register-blocked GEMM ----------------
__global__ __launch_bounds__(256) void conv2_kernel(const float* __restrict__ y1,
    const float* __restrict__ W1, const float* __restrict__ b1,
    const float* __restrict__ scales, float* __restrict__ y2, float* __restrict__ part)
{
    __shared__ float aT[64 * 128];    // [c][r]
    __shared__ float wT[64 * 64];     // [c][o]
    __shared__ float sred[4 * 128];
    __shared__ float ssc[128];
    const int tid = threadIdx.x;
    const int r0 = blockIdx.x * 128;

    if (tid < 128) ssc[tid] = scales[tid];
    {
        const int o = tid & 63;
        const int cseg = (tid >> 6) * 16;
#pragma unroll
        for (int j = 0; j < 4; ++j) {
            const float4 v = *(const float4*)&W1[o * 64 + cseg + j * 4];
            wT[(cseg + j * 4 + 0) * 64 + o] = v.x;
            wT[(cseg + j * 4 + 1) * 64 + o] = v.y;
            wT[(cseg + j * 4 + 2) * 64 + o] = v.z;
            wT[(cseg + j * 4 + 3) * 64 + o] = v.w;
        }
    }
    __syncthreads();
    {
        const int r = tid & 127;
        const int cs = (tid >> 7) * 32;
#pragma unroll
        for (int j = 0; j < 8; ++j) {
            const int c = cs + j * 4;
            const float4 v = *(const float4*)&y1[(size_t)(r0 + r) * 64 + c];
            aT[(c + 0) * 128 + r] = fmaxf(fmaf(ssc[c + 0], v.x, ssc[64 + c + 0]), 0.f);
            aT[(c + 1) * 128 + r] = fmaxf(fmaf(ssc[c + 1], v.y, ssc[64 + c + 1]), 0.f);
            aT[(c + 2) * 128 + r] = fmaxf(fmaf(ssc[c + 2], v.z, ssc[64 + c + 2]), 0.f);
            aT[(c + 3) * 128 + r] = fmaxf(fmaf(ssc[c + 3], v.w, ssc[64 + c + 3]), 0.f);
        }
    }
    __syncthreads();

    const int wv = tid >> 6;
    const int lane = tid & 63;
    const int tr = lane >> 4;
    const int to = lane & 15;
    const int rbase = wv * 32 + tr * 8;
    const int obase = to * 4;

    const float4 bv = *(const float4*)&b1[obase];
    float4 acc[8];
#pragma unroll
    for (int rr = 0; rr < 8; ++rr) acc[rr] = bv;

#pragma unroll 4
    for (int c = 0; c < 64; ++c) {
        const float4 a0 = *(const float4*)&aT[c * 128 + rbase];
        const float4 a1 = *(const float4*)&aT[c * 128 + rbase + 4];
        const float4 wf = *(const float4*)&wT[c * 64 + obase];
        const float ar[8] = {a0.x, a0.y, a0.z, a0.w, a1.x, a1.y, a1.z, a1.w};
#pragma unroll
        for (int rr = 0; rr < 8; ++rr) {
            acc[rr].x = fmaf(ar[rr], wf.x, acc[rr].x);
            acc[rr].y = fmaf(ar[rr], wf.y, acc[rr].y);
            acc[rr].z = fmaf(ar[rr], wf.z, acc[rr].z);
            acc[rr].w = fmaf(ar[rr], wf.w, acc[rr].w);
        }
    }
    float4 s = {0.f, 0.f, 0.f, 0.f}, q = {0.f, 0.f, 0.f, 0.f};
#pragma unroll
    for (int rr = 0; rr < 8; ++rr) {
        *(float4*)&y2[(size_t)(r0 + rbase + rr) * 64 + obase] = acc[rr];
        s.x += acc[rr].x; s.y += acc[rr].y; s.z += acc[rr].z; s.w += acc[rr].w;
        q.x = fmaf(acc[rr].x, acc[rr].x, q.x);
        q.y = fmaf(acc[rr].y, acc[rr].y, q.y);
        q.z = fmaf(acc[rr].z, acc[rr].z, q.z);
        q.w = fmaf(acc[rr].w, acc[rr].w, q.w);
    }
#pragma unroll
    for (int off = 16; off <= 32; off <<= 1) {
        s.x += __shfl_xor(s.x, off); s.y += __shfl_xor(s.y, off);
        s.z += __shfl_xor(s.z, off); s.w += __shfl_xor(s.w, off);
        q.x += __shfl_xor(q.x, off); q.y += __shfl_xor(q.y, off);
        q.z += __shfl_xor(q.z, off); q.w += __shfl_xor(q.w, off);
    }
    if (tr == 0) {
        sred[wv * 128 + obase + 0] = s.x; sred[wv * 128 + obase + 1] = s.y;
        sred[wv * 128 + obase + 2] = s.z; sred[wv * 128 + obase + 3] = s.w;
        sred[wv * 128 + 64 + obase + 0] = q.x; sred[wv * 128 + 64 + obase + 1] = q.y;
        sred[wv * 128 + 64 + obase + 2] = q.z; sred[wv * 128 + 64 + obase + 3] = q.w;
    }
    __syncthreads();
    if (tid < 128) {
        float tot = sred[tid] + sred[128 + tid] + sred[256 + tid] + sred[384 + tid];
        part[(size_t)blockIdx.x * 128 + tid] = tot;
    }
}

// ---------------- Conv3 (64->128) GEMM + stats + packed f16 max/min over K ----------------
__global__ __launch_bounds__(256) void conv3_kernel(const float* __restrict__ y2,
    const float* __restrict__ W2, const float* __restrict__ b2,
    const float* __restrict__ scales, __half2* __restrict__ mxmn, float* __restrict__ part)
{
    __shared__ float aT[64 * 128];    // [c][r]
    __shared__ float wT[64 * 128];    // [c][o]
    __shared__ float sred[4 * 256];
    __shared__ float ssc[128];
    const int tid = threadIdx.x;
    const int r0 = blockIdx.x * 128;

    if (tid < 128) ssc[tid] = scales[128 + tid];
    {
        const int o = tid & 127;
        const int cs = (tid >> 7) * 32;
#pragma unroll
        for (int j = 0; j < 8; ++j) {
            const float4 v = *(const float4*)&W2[(size_t)o * 64 + cs + j * 4];
            wT[(cs + j * 4 + 0) * 128 + o] = v.x;
            wT[(cs + j * 4 + 1) * 128 + o] = v.y;
            wT[(cs + j * 4 + 2) * 128 + o] = v.z;
            wT[(cs + j * 4 + 3) * 128 + o] = v.w;
        }
    }
    __syncthreads();
    {
        const int r = tid & 127;
        const int cs = (tid >> 7) * 32;
#pragma unroll
        for (int j = 0; j < 8; ++j) {
            const int c = cs + j * 4;
            const float4 v = *(const float4*)&y2[(size_t)(r0 + r) * 64 + c];
            aT[(c + 0) * 128 + r] = fmaxf(fmaf(ssc[c + 0], v.x, ssc[64 + c + 0]), 0.f);
            aT[(c + 1) * 128 + r] = fmaxf(fmaf(ssc[c + 1], v.y, ssc[64 + c + 1]), 0.f);
            aT[(c + 2) * 128 + r] = fmaxf(fmaf(ssc[c + 2], v.z, ssc[64 + c + 2]), 0.f);
            aT[(c + 3) * 128 + r] = fmaxf(fmaf(ssc[c + 3], v.w, ssc[64 + c + 3]), 0.f);
        }
    }
    __syncthreads();

    const int wv = tid >> 6;
    const int lane = tid & 63;
    const int tr = lane >> 4;
    const int to = lane & 15;
    const int rbase = wv * 32 + tr * 8;
    const int ol = to * 4;
    const int oh = 64 + to * 4;

    const float4 bl = *(const float4*)&b2[ol];
    const float4 bh = *(const float4*)&b2[oh];
    float4 accl[8], acch[8];
#pragma unroll
    for (int rr = 0; rr < 8; ++rr) { accl[rr] = bl; acch[rr] = bh; }

#pragma unroll 2
    for (int c = 0; c < 64; ++c) {
        const float4 a0 = *(const float4*)&aT[c * 128 + rbase];
        const float4 a1 = *(const float4*)&aT[c * 128 + rbase + 4];
        const float4 w0 = *(const float4*)&wT[c * 128 + ol];
        const float4 w1 = *(const float4*)&wT[c * 128 + oh];
        const float ar[8] = {a0.x, a0.y, a0.z, a0.w, a1.x, a1.y, a1.z, a1.w};
#pragma unroll
        for (int rr = 0; rr < 8; ++rr) {
            accl[rr].x = fmaf(ar[rr], w0.x, accl[rr].x);
            accl[rr].y = fmaf(ar[rr], w0.y, accl[rr].y);
            accl[rr].z = fmaf(ar[rr], w0.z, accl[rr].z);
            accl[rr].w = fmaf(ar[rr], w0.w, accl[rr].w);
            acch[rr].x = fmaf(ar[rr], w1.x, acch[rr].x);
            acch[rr].y = fmaf(ar[rr], w1.y, acch[rr].y);
            acch[rr].z = fmaf(ar[rr], w1.z, acch[rr].z);
            acch[rr].w = fmaf(ar[rr], w1.w, acch[rr].w);
        }
    }
    float4 sl = {0,0,0,0}, ql = {0,0,0,0}, sh4 = {0,0,0,0}, qh = {0,0,0,0};
    float4 mxl = accl[0], mnl = accl[0], mxh = acch[0], mnh = acch[0];
#pragma unroll
    for (int rr = 0; rr < 8; ++rr) {
        sl.x += accl[rr].x; sl.y += accl[rr].y; sl.z += accl[rr].z; sl.w += accl[rr].w;
        sh4.x += acch[rr].x; sh4.y += acch[rr].y; sh4.z += acch[rr].z; sh4.w += acch[rr].w;
        ql.x = fmaf(accl[rr].x, accl[rr].x, ql.x); ql.y = fmaf(accl[rr].y, accl[rr].y, ql.y);
        ql.z = fmaf(accl[rr].z, accl[rr].z, ql.z); ql.w = fmaf(accl[rr].w, accl[rr].w, ql.w);
        qh.x = fmaf(acch[rr].x, acch[rr].x, qh.x); qh.y = fmaf(acch[rr].y, acch[rr].y, qh.y);
        qh.z = fmaf(acch[rr].z, acch[rr].z, qh.z); qh.w = fmaf(acch[rr].w, acch[rr].w, qh.w);
        mxl.x = fmaxf(mxl.x, accl[rr].x); mnl.x = fminf(mnl.x, accl[rr].x);
        mxl.y = fmaxf(mxl.y, accl[rr].y); mnl.y = fminf(mnl.y, accl[rr].y);
        mxl.z = fmaxf(mxl.z, accl[rr].z); mnl.z = fminf(mnl.z, accl[rr].z);
        mxl.w = fmaxf(mxl.w, accl[rr].w); mnl.w = fminf(mnl.w, accl[rr].w);
        mxh.x = fmaxf(mxh.x, acch[rr].x); mnh.x = fminf(mnh.x, acch[rr].x);
        mxh.y = fmaxf(mxh.y, acch[rr].y); mnh.y = fminf(mnh.y, acch[rr].y);
        mxh.z = fmaxf(mxh.z, acch[rr].z); mnh.z = fminf(mnh.z, acch[rr].z);
        mxh.w = fmaxf(mxh.w, acch[rr].w); mnh.w = fminf(mnh.w, acch[rr].w);
    }
#pragma unroll
    for (int off = 16; off <= 32; off <<= 1) {
        sl.x += __shfl_xor(sl.x, off); sl.y += __shfl_xor(sl.y, off);
        sl.z += __shfl_xor(sl.z, off); sl.w += __shfl_xor(sl.w, off);
        sh4.x += __shfl_xor(sh4.x, off); sh4.y += __shfl_xor(sh4.y, off);
        sh4.z += __shfl_xor(sh4.z, off); sh4.w += __shfl_xor(sh4.w, off);
        ql.x += __shfl_xor(ql.x, off); ql.y += __shfl_xor(ql.y, off);
        ql.z += __shfl_xor(ql.z, off); ql.w += __shfl_xor(ql.w, off);
        qh.x += __shfl_xor(qh.x, off); qh.y += __shfl_xor(qh.y, off);
        qh.z += __shfl_xor(qh.z, off); qh.w += __shfl_xor(qh.w, off);
        mxl.x = fmaxf(mxl.x, __shfl_xor(mxl.x, off)); mnl.x = fminf(mnl.x, __shfl_xor(mnl.x, off));
        mxl.y = fmaxf(mxl.y, __shfl_xor(mxl.y, off)); mnl.y = fminf(mnl.y, __shfl_xor(mnl.y, off));
        mxl.z = fmaxf(mxl.z, __shfl_xor(mxl.z, off)); mnl.z = fminf(mnl.z, __shfl_xor(mnl.z, off));
        mxl.w = fmaxf(mxl.w, __shfl_xor(mxl.w, off)); mnl.w = fminf(mnl.w, __shfl_xor(mnl.w, off));
        mxh.x = fmaxf(mxh.x, __shfl_xor(mxh.x, off)); mnh.x = fminf(mnh.x, __shfl_xor(mnh.x, off));
        mxh.y = fmaxf(mxh.y, __shfl_xor(mxh.y, off)); mnh.y = fminf(mnh.y, __shfl_xor(mnh.y, off));
        mxh.z = fmaxf(mxh.z, __shfl_xor(mxh.z, off)); mnh.z = fminf(mnh.z, __shfl_xor(mnh.z, off));
        mxh.w = fmaxf(mxh.w, __shfl_xor(mxh.w, off)); mnh.w = fminf(mnh.w, __shfl_xor(mnh.w, off));
    }
    if (tr == 0) {
        const int wid = blockIdx.x * 4 + wv;
        __half2* mp = mxmn + (size_t)wid * 128;
        mp[ol + 0] = __floats2half2_rn(mxl.x, mnl.x);
        mp[ol + 1] = __floats2half2_rn(mxl.y, mnl.y);
        mp[ol + 2] = __floats2half2_rn(mxl.z, mnl.z);
        mp[ol + 3] = __floats2half2_rn(mxl.w, mnl.w);
        mp[oh + 0] = __floats2half2_rn(mxh.x, mnh.x);
        mp[oh + 1] = __floats2half2_rn(mxh.y, mnh.y);
        mp[oh + 2] = __floats2half2_rn(mxh.z, mnh.z);
        mp[oh + 3] = __floats2half2_rn(mxh.w, mnh.w);
        sred[wv * 256 + ol + 0] = sl.x; sred[wv * 256 + ol + 1] = sl.y;
        sred[wv * 256 + ol + 2] = sl.z; sred[wv * 256 + ol + 3] = sl.w;
        sred[wv * 256 + oh + 0] = sh4.x; sred[wv * 256 + oh + 1] = sh4.y;
        sred[wv * 256 + oh + 2] = sh4.z; sred[wv * 256 + oh + 3] = sh4.w;
        sred[wv * 256 + 128 + ol + 0] = ql.x; sred[wv * 256 + 128 + ol + 1] = ql.y;
        sred[wv * 256 + 128 + ol + 2] = ql.z; sred[wv * 256 + 128 + ol + 3] = ql.w;
        sred[wv * 256 + 128 + oh + 0] = qh.x; sred[wv * 256 + 128 + oh + 1] = qh.y;
        sred[wv * 256 + 128 + oh + 2] = qh.z; sred[wv * 256 + 128 + oh + 3] = qh.w;
    }
    __syncthreads();
    {
        float tot = sred[tid] + sred[256 + tid] + sred[512 + tid] + sred[768 + tid];
        part[(size_t)blockIdx.x * 256 + tid] = tot;
    }
}

// ---------------- BN stats -> per-channel scale/shift ----------------
__global__ __launch_bounds__(1024) void stats_kernel(const float* __restrict__ part,
    int nparts, int nch, const float* __restrict__ g, const float* __restrict__ be,
    float* __restrict__ scale, float* __restrict__ shift)
{
    __shared__ float s_s[1024], s_q[1024];
    const int t = threadIdx.x;
    const int groups = 1024 / nch;
    const int gid = t / nch;
    const int o = t % nch;
    const int chunk = nparts / groups;
    float sum = 0.f, sq = 0.f;
    for (int p = gid * chunk; p < (gid + 1) * chunk; ++p) {
        sum += part[(size_t)p * 2 * nch + o];
        sq  += part[(size_t)p * 2 * nch + nch + o];
    }
    s_s[t] = sum; s_q[t] = sq;
    __syncthreads();
    if (t < nch) {
        float S = 0.f, Q = 0.f;
        for (int gi = 0; gi < groups; ++gi) { S += s_s[gi * nch + o]; Q += s_q[gi * nch + o]; }
        float m = S / CNTF;
        float v = Q / CNTF - m * m;
        v = v < 0.f ? 0.f : v;
        float scv = g[o] / sqrtf(v + 1e-5f);
        scale[o] = scv;
        shift[o] = be[o] - m * scv;
    }
}

// ---------------- Final: BN3+ReLU+max via packed (mx,mn) ----------------
__global__ __launch_bounds__(256) void final_kernel(const __half2* __restrict__ mxmn,
    const float* __restrict__ scales, float* __restrict__ out)
{
    int tid = blockIdx.x * 256 + threadIdx.x;   // b*65536 + o*512 + s
    int b = tid >> 16;
    int o = (tid >> 9) & 127;
    int s = tid & 511;
    int row = (b * NS + s) * 128 + o;
    float sc = scales[256 + o], sh = scales[384 + o];
    const __half2 h = mxmn[row];
    float vmx = __low2float(h), vmn = __high2float(h);
    float y = fmaxf(fmaf(sc, vmx, sh), fmaf(sc, vmn, sh));
    out[tid] = fmaxf(y, 0.f);
}

extern "C" void kernel_launch(void* const* d_in, const int* in_sizes, int n_in,
                              void* d_out, int out_size, void* d_ws, size_t ws_size,
                              hipStream_t stream)
{
    (void)in_sizes; (void)n_in; (void)out_size; (void)ws_size;
    const float* xyz    = (const float*)d_in[0];
    const float* points = (const float*)d_in[1];
    const float* W0  = (const float*)d_in[2];
    const float* b0  = (const float*)d_in[3];
    const float* g0  = (const float*)d_in[4];
    const float* be0 = (const float*)d_in[5];
    const float* W1  = (const float*)d_in[6];
    const float* b1  = (const float*)d_in[7];
    const float* g1  = (const float*)d_in[8];
    const float* be1 = (const float*)d_in[9];
    const float* W2  = (const float*)d_in[10];
    const float* b2  = (const float*)d_in[11];
    const float* g2  = (const float*)d_in[12];
    const float* be2 = (const float*)d_in[13];

    char* ws = (char*)d_ws;
    float*   nxyz = (float*)(ws + O_NXYZ);
    int*     idx  = (int*)(ws + O_IDX);
    float*   scl  = (float*)(ws + O_SC);
    float*   p1   = (float*)(ws + O_P1);
    float*   p2   = (float*)(ws + O_P2);
    float*   p3   = (float*)(ws + O_P3);
    __half2* mxmn = (__half2*)(ws + O_MX);
    float*   y1   = (float*)(ws + O_Y1);
    float*   y2   = (float*)(ws + O_Y2);
    float*   out  = (float*)d_out;

    fps_kernel<<<16, 1024, 0, stream>>>(xyz, out, nxyz);
    ballq_kernel<<<2048, 256, 0, stream>>>(xyz, nxyz, idx);
    conv1_kernel<<<1024, 256, 0, stream>>>(xyz, points, nxyz, idx, W0, b0, y1, p1);
    stats_kernel<<<1, 1024, 0, stream>>>(p1, 1024, 64, g0, be0, scl + 0, scl + 64);
    conv2_kernel<<<2048, 256, 0, stream>>>(y1, W1, b1, scl, y2, p2);
    stats_kernel<<<1, 1024, 0, stream>>>(p2, 2048, 64, g1, be1, scl + 128, scl + 192);
    conv3_kernel<<<2048, 256, 0, stream>>>(y2, W2, b2, scl, mxmn, p3);
    stats_kernel<<<1, 1024, 0, stream>>>(p3, 2048, 128, g2, be2, scl + 256, scl + 384);
    final_kernel<<<4096, 256, 0, stream>>>(mxmn, scl, out + 24576);
}